// Round 10
// baseline (1521.209 us; speedup 1.0000x reference)
//
#include <hip/hip_runtime.h>
#include <hip/hip_bf16.h>
#include <math.h>

constexpr int NN = 100000;     // nodes
constexpr int NE = 3200000;    // edges
constexpr int HID = 256;
constexpr int NBLK = (NN + 255) / 256;   // 391

typedef __attribute__((ext_vector_type(8))) short short8;
typedef __attribute__((ext_vector_type(4))) float floatx4;
typedef __attribute__((ext_vector_type(2))) float floatx2;
typedef __attribute__((ext_vector_type(8))) unsigned short ushort8v;

// ---- bf16 helpers (storage bf16, math fp32) -------------------------------
__device__ __forceinline__ float bf2f(unsigned short u) {
    unsigned int t = ((unsigned int)u) << 16;
    float f; __builtin_memcpy(&f, &t, 4); return f;
}
__device__ __forceinline__ unsigned short f2bf(float f) {
    unsigned int t; __builtin_memcpy(&t, &f, 4);
    unsigned int lsb = (t >> 16) & 1u;
    t += 0x7fffu + lsb;
    return (unsigned short)(t >> 16);
}
// fp8 e4m3 (OCP on gfx950): single-value encode via pk instruction
__device__ __forceinline__ unsigned char f2fp8(float f) {
    int pk = __builtin_amdgcn_cvt_pk_fp8_f32(f, f, 0, false);
    return (unsigned char)(pk & 0xff);
}

// async global->LDS, 16B per lane; lds base must be wave-uniform
__device__ __forceinline__ void llds16(const void* g, void* l) {
    __builtin_amdgcn_global_load_lds(
        (const __attribute__((address_space(1))) unsigned int*)g,
        (__attribute__((address_space(3))) unsigned int*)l, 16, 0, 0);
}

// ---------------------------------------------------------------------------
// Edge dtype detection (int64 vs int32 delivery)
// ---------------------------------------------------------------------------
__global__ void detect_i64(const int* __restrict__ ei, int* __restrict__ flag) {
    if (blockIdx.x == 0 && threadIdx.x == 0) {
        int z = 1;
        for (int i = 0; i < 64; ++i)
            if (ei[2 * i + 1] != 0) { z = 0; break; }
        *flag = z;
    }
}
__device__ __forceinline__ int load_edge(const int* ei, int is64, long long idx) {
    if (is64) return (int)(((const long long*)ei)[idx]);
    return ei[idx];
}

__global__ void zero_setup(int* __restrict__ cnt, int* __restrict__ cursor,
                           float* __restrict__ gsum) {
    int i = blockIdx.x * 256 + threadIdx.x;
    if (i < NN) { cnt[i] = 0; cursor[i] = 0; }
    if (i < HID) gsum[i] = 0.0f;
}

// ---------------------------------------------------------------------------
// Weight / input conversion to bf16
// wcf[n][k] = {W_f[n][k] k<256 ; U_f[n][k-256]}  (row 1 KB)   same for wch
// ---------------------------------------------------------------------------
__global__ void conv_weights(const float* __restrict__ Wf, const float* __restrict__ Uf,
                             const float* __restrict__ Wh, const float* __restrict__ Uh,
                             const float* __restrict__ Win,
                             unsigned short* __restrict__ wcf,
                             unsigned short* __restrict__ wch,
                             unsigned short* __restrict__ wib) {
    int i = blockIdx.x * 256 + threadIdx.x;
    if (i < 256 * 512) {
        int n = i >> 9, k = i & 511;
        float vf = (k < 256) ? Wf[n * 256 + k] : Uf[n * 256 + k - 256];
        float vh = (k < 256) ? Wh[n * 256 + k] : Uh[n * 256 + k - 256];
        wcf[i] = f2bf(vf); wch[i] = f2bf(vh);
    }
    if (i < 128 * 128) wib[i] = f2bf(Win[i]);
}

__global__ void conv_x(const float* __restrict__ x, unsigned short* __restrict__ xb) {
    int i = blockIdx.x * 256 + threadIdx.x;   // one float4 each
    if (i < NN * 128 / 4) {
        float4 v = ((const float4*)x)[i];
        ushort4 o;
        o.x = f2bf(v.x); o.y = f2bf(v.y); o.z = f2bf(v.z); o.w = f2bf(v.w);
        ((ushort4*)xb)[i] = o;
    }
}

// ---------------------------------------------------------------------------
// CSR construction
// ---------------------------------------------------------------------------
__global__ void count_deg(const int* __restrict__ ei, const int* __restrict__ flag,
                          int* __restrict__ cnt) {
    int e = blockIdx.x * 256 + threadIdx.x;
    if (e >= NE) return;
    int is64 = *flag;
    int d = load_edge(ei, is64, (long long)NE + e);
    d = min(max(d, 0), NN - 1);
    atomicAdd(&cnt[d], 1);
}

// hierarchical scan: k1 per-block scan, k2 scan block sums, k3 combine
__global__ void scan_k1(const int* __restrict__ cnt, int* __restrict__ loc,
                        int* __restrict__ bsum) {
    __shared__ int s[256];
    int b = blockIdx.x, t = threadIdx.x;
    int i = b * 256 + t;
    int v = (i < NN) ? cnt[i] : 0;
    s[t] = v;
    __syncthreads();
    for (int ofs = 1; ofs < 256; ofs <<= 1) {
        int tv = (t >= ofs) ? s[t - ofs] : 0;
        __syncthreads();
        s[t] += tv;
        __syncthreads();
    }
    if (i < NN) loc[i] = s[t] - v;          // exclusive
    if (t == 255) bsum[b] = s[255];
}
__global__ void scan_k2(const int* __restrict__ bsum, int* __restrict__ bpre) {
    __shared__ int s[512];
    int t = threadIdx.x;
    int v = (t < NBLK) ? bsum[t] : 0;
    s[t] = v;
    __syncthreads();
    for (int ofs = 1; ofs < 512; ofs <<= 1) {
        int tv = (t >= ofs) ? s[t - ofs] : 0;
        __syncthreads();
        s[t] += tv;
        __syncthreads();
    }
    if (t < NBLK) bpre[t] = s[t] - v;       // exclusive
    if (t == NBLK - 1) bpre[NBLK] = s[t];   // total
}
// also primes cursor[i] = off[i] so fill_csr needs ONE random access per edge
__global__ void scan_k3(const int* __restrict__ loc, const int* __restrict__ bpre,
                        int* __restrict__ off, int* __restrict__ cursor) {
    int b = blockIdx.x, t = threadIdx.x;
    int i = b * 256 + t;
    if (i < NN) {
        int v = loc[i] + bpre[b];
        off[i] = v;
        cursor[i] = v;
    }
    if (b == 0 && t == 0) off[NN] = bpre[NBLK];
}

// cursor pre-primed with off -> atomicAdd returns the absolute csr slot
__global__ void fill_csr(const int* __restrict__ ei, const int* __restrict__ flag,
                         int* __restrict__ cursor, int* __restrict__ csr) {
    int e = blockIdx.x * 256 + threadIdx.x;
    if (e >= NE) return;
    int is64 = *flag;
    int s = load_edge(ei, is64, e);
    int d = load_edge(ei, is64, (long long)NE + e);
    s = min(max(s, 0), NN - 1);
    d = min(max(d, 0), NN - 1);
    int p = atomicAdd(&cursor[d], 1);
    csr[p] = s;
}

// ---------------------------------------------------------------------------
// fp8 aggregation: mean of hq[src] rows per node. hq is fp8 e4m3 [NN][256].
// 2 feature chunks of 128 feats (= exactly one 128B L2 line per edge read).
// One wave per node per chunk: 8 edge-slots x 8 feature-lanes (16B/lane).
// unroll-4 (32 edges/group) covers typical deg~32 with 4 loads in flight.
// ---------------------------------------------------------------------------
__device__ __forceinline__ void acc16(floatx2 (&a)[8], uint4 v) {
    unsigned int d[4] = {v.x, v.y, v.z, v.w};
#pragma unroll
    for (int q = 0; q < 4; ++q) {
        floatx2 lo = __builtin_amdgcn_cvt_pk_f32_fp8(d[q], false);
        floatx2 hi = __builtin_amdgcn_cvt_pk_f32_fp8(d[q], true);
        a[q * 2 + 0] += lo;
        a[q * 2 + 1] += hi;
    }
}

__global__ __launch_bounds__(256)
void agg8(const unsigned char* __restrict__ hq, const int* __restrict__ off,
          const int* __restrict__ csr, unsigned short* __restrict__ m) {
    int node = blockIdx.x * 4 + (threadIdx.x >> 6);
    int lane = threadIdx.x & 63;
    int eslot = lane >> 3;              // 0..7: which edge of the group of 8
    int fl = lane & 7;                  // 16-feature (16B) chunk within slice
    int fbase = blockIdx.y * 128;       // feature chunk base (0 or 128)
    int e0 = off[node], e1 = off[node + 1];
    const unsigned char* hp = hq + fbase + fl * 16;
    floatx2 a0[8], a1[8];
#pragma unroll
    for (int k = 0; k < 8; ++k) {
        a0[k][0] = 0.f; a0[k][1] = 0.f;
        a1[k][0] = 0.f; a1[k][1] = 0.f;
    }
    int e = e0;
    for (; e + 32 <= e1; e += 32) {     // 4 independent loads in flight
        int s0 = csr[e + eslot];
        int s1 = csr[e + 8 + eslot];
        int s2 = csr[e + 16 + eslot];
        int s3 = csr[e + 24 + eslot];
        uint4 v0 = *(const uint4*)(hp + (size_t)s0 * 256);
        uint4 v1 = *(const uint4*)(hp + (size_t)s1 * 256);
        uint4 v2 = *(const uint4*)(hp + (size_t)s2 * 256);
        uint4 v3 = *(const uint4*)(hp + (size_t)s3 * 256);
        acc16(a0, v0);
        acc16(a1, v1);
        acc16(a0, v2);
        acc16(a1, v3);
    }
    for (; e + 16 <= e1; e += 16) {
        int s0 = csr[e + eslot];
        int s1 = csr[e + 8 + eslot];
        uint4 v0 = *(const uint4*)(hp + (size_t)s0 * 256);
        uint4 v1 = *(const uint4*)(hp + (size_t)s1 * 256);
        acc16(a0, v0);
        acc16(a1, v1);
    }
    for (; e + 8 <= e1; e += 8) {
        int s0 = csr[e + eslot];
        uint4 v0 = *(const uint4*)(hp + (size_t)s0 * 256);
        acc16(a0, v0);
    }
    if (e + eslot < e1) {
        int s0 = csr[e + eslot];
        uint4 v0 = *(const uint4*)(hp + (size_t)s0 * 256);
        acc16(a1, v0);
    }
#pragma unroll
    for (int k = 0; k < 8; ++k) a0[k] += a1[k];
    // reduce over the 8 edge-slots (lanes differing in bits 3..5)
#pragma unroll
    for (int k = 0; k < 8; ++k) {
#pragma unroll
        for (int c = 0; c < 2; ++c) {
            a0[k][c] += __shfl_xor(a0[k][c], 8, 64);
            a0[k][c] += __shfl_xor(a0[k][c], 16, 64);
            a0[k][c] += __shfl_xor(a0[k][c], 32, 64);
        }
    }
    float inv = 1.0f / (float)max(e1 - e0, 1);
    if (eslot == 0) {
        ushort8v o0, o1;
#pragma unroll
        for (int k = 0; k < 8; ++k) {
            o0[k] = f2bf(a0[k >> 1][k & 1] * inv);
            o1[k] = f2bf(a0[4 + (k >> 1)][k & 1] * inv);
        }
        unsigned short* mp = m + (size_t)node * HID + fbase + fl * 16;
        *(ushort8v*)mp = o0;
        *(ushort8v*)(mp + 8) = o1;
    }
}

// ---------------------------------------------------------------------------
// Encode GEMM, 128x128 tile, 4 waves (2x2), each wave 4x4 of 16x16x32 bf16.
// out = relu(x @ W_in^T + b_in) -> hbuf[:, :128] bf16 + hq fp8; cols 128.. = 0
// ---------------------------------------------------------------------------
__global__ __launch_bounds__(256)
void gemm_encode(const unsigned short* __restrict__ A0,
                 const unsigned short* __restrict__ Bw,
                 const float* __restrict__ bias,
                 unsigned short* Out,
                 unsigned char* Hq) {
    __shared__ unsigned short As[128 * 32];
    __shared__ unsigned short Bs[128 * 32];

    const int tid = threadIdx.x;
    const int wave = tid >> 6, lane = tid & 63;
    const int wr = (wave >> 1) * 64, wc = (wave & 1) * 64;
    const int lq = lane >> 4, lm = lane & 15;
    const int rowBase = blockIdx.x * 128;

    floatx4 acc[4][4];
#pragma unroll
    for (int i = 0; i < 4; ++i)
#pragma unroll
        for (int j = 0; j < 4; ++j) {
            acc[i][j][0] = 0.f; acc[i][j][1] = 0.f;
            acc[i][j][2] = 0.f; acc[i][j][3] = 0.f;
        }

    for (int k0 = 0; k0 < 128; k0 += 32) {
#pragma unroll
        for (int q = 0; q < 2; ++q) {
            int id = wave * 128 + q * 64 + lane;
            int r = id >> 2, c = id & 3;
            int grow = rowBase + r;
            if (grow > NN - 1) grow = NN - 1;
            llds16((const char*)A0 + (size_t)grow * 256 + k0 * 2 + c * 16,
                   (char*)As + (size_t)(wave * 128 + q * 64) * 16);
            llds16((const char*)Bw + (size_t)r * 256 + k0 * 2 + c * 16,
                   (char*)Bs + (size_t)(wave * 128 + q * 64) * 16);
        }
        __syncthreads();
        short8 af[4], bf_[4];
#pragma unroll
        for (int i = 0; i < 4; ++i)
            af[i] = *(const short8*)&As[(wr + i * 16 + lm) * 32 + lq * 8];
#pragma unroll
        for (int j = 0; j < 4; ++j)
            bf_[j] = *(const short8*)&Bs[(wc + j * 16 + lm) * 32 + lq * 8];
#pragma unroll
        for (int i = 0; i < 4; ++i)
#pragma unroll
            for (int j = 0; j < 4; ++j)
                acc[i][j] = __builtin_amdgcn_mfma_f32_16x16x32_bf16(
                    af[i], bf_[j], acc[i][j], 0, 0, 0);
        __syncthreads();
    }

#pragma unroll
    for (int i = 0; i < 4; ++i) {
#pragma unroll
        for (int r = 0; r < 4; ++r) {
            int row = rowBase + wr + i * 16 + lq * 4 + r;
            if (row >= NN) continue;
            size_t rb = (size_t)row * HID;
#pragma unroll
            for (int j = 0; j < 4; ++j) {
                int col = wc + j * 16 + lm;
                float v = acc[i][j][r] + bias[col];
                float rv = fmaxf(v, 0.f);
                Out[rb + col] = f2bf(rv);
                Out[rb + col + 128] = 0;
                Hq[rb + col] = f2fp8(rv);
                Hq[rb + col + 128] = 0;
            }
        }
    }
}

// ---------------------------------------------------------------------------
// Wide MFMA GEMM for the MGU steps: 64x256 tile, 256 threads = 4 waves
// (1 row-group x 4 col-groups), each wave 64x64 = 4x4 of 16x16x32.
// Retiled from 128x256/512thr to raise block-level phase diversity:
// LDS 40 KB -> 4 blocks/CU (VGPR<=128 keeps 16 waves/CU) vs 2 before.
// BK=64 + XOR bank-swizzle (chunk ^= row&7) both sides (rule #21).
// MODE 1: gate  f = sigmoid(v+b_f) -> Ff;  HF = f * Hh
// MODE 2: cand  Out = (1-f)*h + f*tanh(v+b_h); Hq = fp8(Out)
// ---------------------------------------------------------------------------
template <int MODE>
__global__ __launch_bounds__(256, 4)
void gemm_wide(const unsigned short* __restrict__ A0,
               const unsigned short* __restrict__ A1,
               const unsigned short* __restrict__ Bw,
               const float* __restrict__ bias,
               const unsigned short* __restrict__ Hh,
               unsigned short* __restrict__ Ff,
               unsigned short* __restrict__ HF,
               unsigned short* __restrict__ Out,
               unsigned char* __restrict__ Hq) {
    __shared__ unsigned short As[64 * 64];    //  8 KB, rows 128 B, swizzled
    __shared__ unsigned short Bs[256 * 64];   // 32 KB

    const int tid = threadIdx.x;
    const int wave = tid >> 6, lane = tid & 63;
    const int wc = wave * 64;
    const int lq = lane >> 4, lm = lane & 15;
    const int rowBase = blockIdx.x * 64;

    floatx4 acc[4][4];
#pragma unroll
    for (int i = 0; i < 4; ++i)
#pragma unroll
        for (int j = 0; j < 4; ++j) {
            acc[i][j][0] = 0.f; acc[i][j][1] = 0.f;
            acc[i][j][2] = 0.f; acc[i][j][3] = 0.f;
        }

    for (int k0 = 0; k0 < 512; k0 += 64) {
        const unsigned short* Alo = (k0 >= 256) ? A1 : A0;
        const int kc = k0 & 255;
        // stage A: 8 KB = 2 passes x 256 threads x 16 B; source pre-swizzled
#pragma unroll
        for (int p = 0; p < 2; ++p) {
            int id = p * 256 + tid;
            int r = id >> 3, c = id & 7;
            int cs = c ^ (r & 7);
            int grow = rowBase + r;
            if (grow > NN - 1) grow = NN - 1;
            llds16((const char*)Alo + (size_t)grow * 512 + kc * 2 + cs * 16,
                   (char*)As + p * 4096 + wave * 1024);
        }
        // stage B: 32 KB = 8 passes x 256 threads x 16 B
#pragma unroll
        for (int p = 0; p < 8; ++p) {
            int id = p * 256 + tid;
            int r = id >> 3, c = id & 7;
            int cs = c ^ (r & 7);
            llds16((const char*)Bw + (size_t)r * 1024 + k0 * 2 + cs * 16,
                   (char*)Bs + p * 4096 + wave * 1024);
        }
        __syncthreads();
#pragma unroll
        for (int ks = 0; ks < 2; ++ks) {
            short8 af[4], bfr[4];
#pragma unroll
            for (int i = 0; i < 4; ++i) {
                int r = i * 16 + lm;
                int cc = (ks * 4 + lq) ^ (r & 7);      // inverse swizzle on read
                af[i] = *(const short8*)((const char*)As + r * 128 + cc * 16);
            }
#pragma unroll
            for (int j = 0; j < 4; ++j) {
                int r = wc + j * 16 + lm;
                int cc = (ks * 4 + lq) ^ (r & 7);
                bfr[j] = *(const short8*)((const char*)Bs + r * 128 + cc * 16);
            }
#pragma unroll
            for (int i = 0; i < 4; ++i)
#pragma unroll
                for (int j = 0; j < 4; ++j)
                    acc[i][j] = __builtin_amdgcn_mfma_f32_16x16x32_bf16(
                        af[i], bfr[j], acc[i][j], 0, 0, 0);
        }
        __syncthreads();
    }

    // epilogue
#pragma unroll
    for (int i = 0; i < 4; ++i) {
#pragma unroll
        for (int r = 0; r < 4; ++r) {
            int row = rowBase + i * 16 + lq * 4 + r;
            if (row >= NN) continue;
            size_t rb = (size_t)row * HID;
#pragma unroll
            for (int j = 0; j < 4; ++j) {
                int col = wc + j * 16 + lm;
                float v = acc[i][j][r] + bias[col];
                if (MODE == 1) {
                    float f = 1.f / (1.f + __expf(-v));
                    float hv = bf2f(Hh[rb + col]);
                    Ff[rb + col] = f2bf(f);
                    HF[rb + col] = f2bf(f * hv);
                } else {
                    float xc = fminf(fmaxf(v, -12.f), 12.f);
                    float e2 = __expf(2.f * xc);
                    float t = (e2 - 1.f) / (e2 + 1.f);
                    float f = bf2f(Ff[rb + col]);
                    float hv = bf2f(Hh[rb + col]);
                    float nh = (1.f - f) * hv + f * t;
                    Out[rb + col] = f2bf(nh);
                    Hq[rb + col] = f2fp8(nh);
                }
            }
        }
    }
}

// ---------------------------------------------------------------------------
// Readout
// ---------------------------------------------------------------------------
__global__ __launch_bounds__(256)
void colmean(const unsigned short* __restrict__ h, float* __restrict__ gsum) {
    int j = threadIdx.x;
    long long n0 = (long long)blockIdx.x * 256;
    float acc = 0.0f;
    for (int n = 0; n < 256; ++n) {
        long long node = n0 + n;
        if (node < NN) acc += bf2f(h[node * HID + j]);
    }
    atomicAdd(&gsum[j], acc);
}

__global__ __launch_bounds__(256)
void final_pred(const float* __restrict__ gsum, const float* __restrict__ Wp,
                const float* __restrict__ bp, float* __restrict__ out) {
    __shared__ float s[256];
    int j = threadIdx.x;
    s[j] = gsum[j] * (1.0f / (float)NN) * Wp[j];
    __syncthreads();
    for (int ofs = 128; ofs > 0; ofs >>= 1) {
        if (j < ofs) s[j] += s[j + ofs];
        __syncthreads();
    }
    if (j == 0) out[0] = s[0] + bp[0];
}

// ---------------------------------------------------------------------------
extern "C" void kernel_launch(void* const* d_in, const int* in_sizes, int n_in,
                              void* d_out, int out_size, void* d_ws, size_t ws_size,
                              hipStream_t stream) {
    const float* x      = (const float*)d_in[0];
    const int*   ei     = (const int*)d_in[1];
    const float* W_in   = (const float*)d_in[2];
    const float* b_in   = (const float*)d_in[3];
    const float* W_f    = (const float*)d_in[4];
    const float* U_f    = (const float*)d_in[5];
    const float* b_f    = (const float*)d_in[6];
    const float* W_h    = (const float*)d_in[7];
    const float* U_h    = (const float*)d_in[8];
    const float* b_h    = (const float*)d_in[9];
    const float* W_pred = (const float*)d_in[10];
    const float* b_pred = (const float*)d_in[11];
    float* out = (float*)d_out;

    char* p = (char*)d_ws;
    auto alloc = [&](size_t bytes) {
        char* r = p;
        p += (bytes + 511) & ~(size_t)511;
        return r;
    };
    int*            cnt    = (int*)alloc((size_t)NN * 4);
    int*            cursor = (int*)alloc((size_t)NN * 4);
    int*            off    = (int*)alloc((size_t)(NN + 1) * 4);
    int*            flag   = (int*)alloc(4);
    float*          gsum   = (float*)alloc(HID * 4);
    int*            loc    = (int*)alloc((size_t)NN * 4);
    int*            bsum   = (int*)alloc((size_t)NBLK * 4);
    int*            bpre   = (int*)alloc((size_t)(NBLK + 1) * 4);
    unsigned short* wcf    = (unsigned short*)alloc((size_t)256 * 512 * 2);
    unsigned short* wch    = (unsigned short*)alloc((size_t)256 * 512 * 2);
    unsigned short* wib    = (unsigned short*)alloc((size_t)128 * 128 * 2);
    int*            csr    = (int*)alloc((size_t)NE * 4);
    unsigned short* hbuf   = (unsigned short*)alloc((size_t)NN * HID * 2);
    unsigned short* mbuf   = (unsigned short*)alloc((size_t)NN * HID * 2);
    unsigned short* fbuf   = (unsigned short*)alloc((size_t)NN * HID * 2);
    unsigned short* hf     = (unsigned short*)alloc((size_t)NN * HID * 2);
    unsigned char*  hq     = (unsigned char*)alloc((size_t)NN * HID);
    unsigned short* xb     = hf;   // xb (25.6MB) used only before hf is live

    detect_i64<<<1, 64, 0, stream>>>(ei, flag);
    zero_setup<<<NBLK, 256, 0, stream>>>(cnt, cursor, gsum);
    conv_weights<<<512, 256, 0, stream>>>(W_f, U_f, W_h, U_h, W_in, wcf, wch, wib);
    conv_x<<<(NN * 128 / 4 + 255) / 256, 256, 0, stream>>>(x, xb);

    count_deg<<<(NE + 255) / 256, 256, 0, stream>>>(ei, flag, cnt);
    scan_k1<<<NBLK, 256, 0, stream>>>(cnt, loc, bsum);
    scan_k2<<<1, 512, 0, stream>>>(bsum, bpre);
    scan_k3<<<NBLK, 256, 0, stream>>>(loc, bpre, off, cursor);
    fill_csr<<<(NE + 255) / 256, 256, 0, stream>>>(ei, flag, cursor, csr);

    // input encode: h = relu(x @ W_in^T + b_in), zero-padded to 256 (+fp8 copy)
    gemm_encode<<<dim3((NN + 127) / 128), 256, 0, stream>>>(xb, wib, b_in, hbuf, hq);

    const int GBLK = (NN + 63) / 64;   // 1563
    for (int step = 0; step < 4; ++step) {
        agg8<<<dim3(NN / 4, 2), 256, 0, stream>>>(hq, off, csr, mbuf);
        gemm_wide<1><<<dim3(GBLK), 256, 0, stream>>>(
            mbuf, hbuf, wcf, b_f, hbuf, fbuf, hf, nullptr, nullptr);
        gemm_wide<2><<<dim3(GBLK), 256, 0, stream>>>(
            mbuf, hf, wch, b_h, hbuf, fbuf, nullptr, hbuf, hq);
    }

    colmean<<<NBLK, 256, 0, stream>>>(hbuf, gsum);
    final_pred<<<1, 256, 0, stream>>>(gsum, W_pred, b_pred, out);
}

// Round 11
// 1439.281 us; speedup vs baseline: 1.0569x; 1.0569x over previous
//
#include <hip/hip_runtime.h>
#include <hip/hip_bf16.h>
#include <math.h>

constexpr int NN = 100000;     // nodes
constexpr int NE = 3200000;    // edges
constexpr int HID = 256;
constexpr int NBLK = (NN + 255) / 256;   // 391

typedef __attribute__((ext_vector_type(8))) short short8;
typedef __attribute__((ext_vector_type(4))) float floatx4;
typedef __attribute__((ext_vector_type(2))) float floatx2;
typedef __attribute__((ext_vector_type(8))) unsigned short ushort8v;

// ---- bf16 helpers (storage bf16, math fp32) -------------------------------
__device__ __forceinline__ float bf2f(unsigned short u) {
    unsigned int t = ((unsigned int)u) << 16;
    float f; __builtin_memcpy(&f, &t, 4); return f;
}
__device__ __forceinline__ unsigned short f2bf(float f) {
    unsigned int t; __builtin_memcpy(&t, &f, 4);
    unsigned int lsb = (t >> 16) & 1u;
    t += 0x7fffu + lsb;
    return (unsigned short)(t >> 16);
}
// fp8 e4m3 (OCP on gfx950): single-value encode via pk instruction
__device__ __forceinline__ unsigned char f2fp8(float f) {
    int pk = __builtin_amdgcn_cvt_pk_fp8_f32(f, f, 0, false);
    return (unsigned char)(pk & 0xff);
}

// async global->LDS, 16B per lane; lds base must be wave-uniform
__device__ __forceinline__ void llds16(const void* g, void* l) {
    __builtin_amdgcn_global_load_lds(
        (const __attribute__((address_space(1))) unsigned int*)g,
        (__attribute__((address_space(3))) unsigned int*)l, 16, 0, 0);
}

// ---------------------------------------------------------------------------
// Edge dtype detection (int64 vs int32 delivery)
// ---------------------------------------------------------------------------
__global__ void detect_i64(const int* __restrict__ ei, int* __restrict__ flag) {
    if (blockIdx.x == 0 && threadIdx.x == 0) {
        int z = 1;
        for (int i = 0; i < 64; ++i)
            if (ei[2 * i + 1] != 0) { z = 0; break; }
        *flag = z;
    }
}
__device__ __forceinline__ int load_edge(const int* ei, int is64, long long idx) {
    if (is64) return (int)(((const long long*)ei)[idx]);
    return ei[idx];
}

__global__ void zero_setup(int* __restrict__ cnt, int* __restrict__ cursor,
                           float* __restrict__ gsum) {
    int i = blockIdx.x * 256 + threadIdx.x;
    if (i < NN) { cnt[i] = 0; cursor[i] = 0; }
    if (i < HID) gsum[i] = 0.0f;
}

// ---------------------------------------------------------------------------
// Weight / input conversion to bf16
// wcf[n][k] = {W_f[n][k] k<256 ; U_f[n][k-256]}  (row 1 KB)   same for wch
// ---------------------------------------------------------------------------
__global__ void conv_weights(const float* __restrict__ Wf, const float* __restrict__ Uf,
                             const float* __restrict__ Wh, const float* __restrict__ Uh,
                             const float* __restrict__ Win,
                             unsigned short* __restrict__ wcf,
                             unsigned short* __restrict__ wch,
                             unsigned short* __restrict__ wib) {
    int i = blockIdx.x * 256 + threadIdx.x;
    if (i < 256 * 512) {
        int n = i >> 9, k = i & 511;
        float vf = (k < 256) ? Wf[n * 256 + k] : Uf[n * 256 + k - 256];
        float vh = (k < 256) ? Wh[n * 256 + k] : Uh[n * 256 + k - 256];
        wcf[i] = f2bf(vf); wch[i] = f2bf(vh);
    }
    if (i < 128 * 128) wib[i] = f2bf(Win[i]);
}

__global__ void conv_x(const float* __restrict__ x, unsigned short* __restrict__ xb) {
    int i = blockIdx.x * 256 + threadIdx.x;   // one float4 each
    if (i < NN * 128 / 4) {
        float4 v = ((const float4*)x)[i];
        ushort4 o;
        o.x = f2bf(v.x); o.y = f2bf(v.y); o.z = f2bf(v.z); o.w = f2bf(v.w);
        ((ushort4*)xb)[i] = o;
    }
}

// ---------------------------------------------------------------------------
// CSR construction
// ---------------------------------------------------------------------------
__global__ void count_deg(const int* __restrict__ ei, const int* __restrict__ flag,
                          int* __restrict__ cnt) {
    int e = blockIdx.x * 256 + threadIdx.x;
    if (e >= NE) return;
    int is64 = *flag;
    int d = load_edge(ei, is64, (long long)NE + e);
    d = min(max(d, 0), NN - 1);
    atomicAdd(&cnt[d], 1);
}

// hierarchical scan: k1 per-block scan, k2 scan block sums, k3 combine
__global__ void scan_k1(const int* __restrict__ cnt, int* __restrict__ loc,
                        int* __restrict__ bsum) {
    __shared__ int s[256];
    int b = blockIdx.x, t = threadIdx.x;
    int i = b * 256 + t;
    int v = (i < NN) ? cnt[i] : 0;
    s[t] = v;
    __syncthreads();
    for (int ofs = 1; ofs < 256; ofs <<= 1) {
        int tv = (t >= ofs) ? s[t - ofs] : 0;
        __syncthreads();
        s[t] += tv;
        __syncthreads();
    }
    if (i < NN) loc[i] = s[t] - v;          // exclusive
    if (t == 255) bsum[b] = s[255];
}
__global__ void scan_k2(const int* __restrict__ bsum, int* __restrict__ bpre) {
    __shared__ int s[512];
    int t = threadIdx.x;
    int v = (t < NBLK) ? bsum[t] : 0;
    s[t] = v;
    __syncthreads();
    for (int ofs = 1; ofs < 512; ofs <<= 1) {
        int tv = (t >= ofs) ? s[t - ofs] : 0;
        __syncthreads();
        s[t] += tv;
        __syncthreads();
    }
    if (t < NBLK) bpre[t] = s[t] - v;       // exclusive
    if (t == NBLK - 1) bpre[NBLK] = s[t];   // total
}
__global__ void scan_k3(const int* __restrict__ loc, const int* __restrict__ bpre,
                        int* __restrict__ off) {
    int b = blockIdx.x, t = threadIdx.x;
    int i = b * 256 + t;
    if (i < NN) off[i] = loc[i] + bpre[b];
    if (b == 0 && t == 0) off[NN] = bpre[NBLK];
}

// r10 lesson: cursor primed-by-scan_k3 regressed fill_csr 167->272 us
// (freshly-dirty cursor lines serialize cross-XCD atomic migration).
// Keep the r8 form: cursor zeroed early, off[d] read-shared.
__global__ void fill_csr(const int* __restrict__ ei, const int* __restrict__ flag,
                         const int* __restrict__ off, int* __restrict__ cursor,
                         int* __restrict__ csr) {
    int e = blockIdx.x * 256 + threadIdx.x;
    if (e >= NE) return;
    int is64 = *flag;
    int s = load_edge(ei, is64, e);
    int d = load_edge(ei, is64, (long long)NE + e);
    s = min(max(s, 0), NN - 1);
    d = min(max(d, 0), NN - 1);
    int p = atomicAdd(&cursor[d], 1);
    csr[off[d] + p] = s;
}

// ---------------------------------------------------------------------------
// fp8 aggregation: mean of hq[src] rows per node. hq is fp8 e4m3 [NN][256].
// 2 feature chunks of 128 feats (= exactly one 128B L2 line per edge read).
// One wave per node per chunk: 8 edge-slots x 8 feature-lanes (16B/lane).
// unroll-4 (32 edges/group) covers typical deg~32 with 4 loads in flight.
// ---------------------------------------------------------------------------
__device__ __forceinline__ void acc16(floatx2 (&a)[8], uint4 v) {
    unsigned int d[4] = {v.x, v.y, v.z, v.w};
#pragma unroll
    for (int q = 0; q < 4; ++q) {
        floatx2 lo = __builtin_amdgcn_cvt_pk_f32_fp8(d[q], false);
        floatx2 hi = __builtin_amdgcn_cvt_pk_f32_fp8(d[q], true);
        a[q * 2 + 0] += lo;
        a[q * 2 + 1] += hi;
    }
}

__global__ __launch_bounds__(256)
void agg8(const unsigned char* __restrict__ hq, const int* __restrict__ off,
          const int* __restrict__ csr, unsigned short* __restrict__ m) {
    int node = blockIdx.x * 4 + (threadIdx.x >> 6);
    int lane = threadIdx.x & 63;
    int eslot = lane >> 3;              // 0..7: which edge of the group of 8
    int fl = lane & 7;                  // 16-feature (16B) chunk within slice
    int fbase = blockIdx.y * 128;       // feature chunk base (0 or 128)
    int e0 = off[node], e1 = off[node + 1];
    const unsigned char* hp = hq + fbase + fl * 16;
    floatx2 a0[8], a1[8];
#pragma unroll
    for (int k = 0; k < 8; ++k) {
        a0[k][0] = 0.f; a0[k][1] = 0.f;
        a1[k][0] = 0.f; a1[k][1] = 0.f;
    }
    int e = e0;
    for (; e + 32 <= e1; e += 32) {     // 4 independent loads in flight
        int s0 = csr[e + eslot];
        int s1 = csr[e + 8 + eslot];
        int s2 = csr[e + 16 + eslot];
        int s3 = csr[e + 24 + eslot];
        uint4 v0 = *(const uint4*)(hp + (size_t)s0 * 256);
        uint4 v1 = *(const uint4*)(hp + (size_t)s1 * 256);
        uint4 v2 = *(const uint4*)(hp + (size_t)s2 * 256);
        uint4 v3 = *(const uint4*)(hp + (size_t)s3 * 256);
        acc16(a0, v0);
        acc16(a1, v1);
        acc16(a0, v2);
        acc16(a1, v3);
    }
    for (; e + 16 <= e1; e += 16) {
        int s0 = csr[e + eslot];
        int s1 = csr[e + 8 + eslot];
        uint4 v0 = *(const uint4*)(hp + (size_t)s0 * 256);
        uint4 v1 = *(const uint4*)(hp + (size_t)s1 * 256);
        acc16(a0, v0);
        acc16(a1, v1);
    }
    for (; e + 8 <= e1; e += 8) {
        int s0 = csr[e + eslot];
        uint4 v0 = *(const uint4*)(hp + (size_t)s0 * 256);
        acc16(a0, v0);
    }
    if (e + eslot < e1) {
        int s0 = csr[e + eslot];
        uint4 v0 = *(const uint4*)(hp + (size_t)s0 * 256);
        acc16(a1, v0);
    }
#pragma unroll
    for (int k = 0; k < 8; ++k) a0[k] += a1[k];
    // reduce over the 8 edge-slots (lanes differing in bits 3..5)
#pragma unroll
    for (int k = 0; k < 8; ++k) {
#pragma unroll
        for (int c = 0; c < 2; ++c) {
            a0[k][c] += __shfl_xor(a0[k][c], 8, 64);
            a0[k][c] += __shfl_xor(a0[k][c], 16, 64);
            a0[k][c] += __shfl_xor(a0[k][c], 32, 64);
        }
    }
    float inv = 1.0f / (float)max(e1 - e0, 1);
    if (eslot == 0) {
        ushort8v o0, o1;
#pragma unroll
        for (int k = 0; k < 8; ++k) {
            o0[k] = f2bf(a0[k >> 1][k & 1] * inv);
            o1[k] = f2bf(a0[4 + (k >> 1)][k & 1] * inv);
        }
        unsigned short* mp = m + (size_t)node * HID + fbase + fl * 16;
        *(ushort8v*)mp = o0;
        *(ushort8v*)(mp + 8) = o1;
    }
}

// ---------------------------------------------------------------------------
// Encode GEMM, 128x128 tile, 4 waves (2x2), each wave 4x4 of 16x16x32 bf16.
// out = relu(x @ W_in^T + b_in) -> hbuf[:, :128] bf16 + hq fp8; cols 128.. = 0
// ---------------------------------------------------------------------------
__global__ __launch_bounds__(256)
void gemm_encode(const unsigned short* __restrict__ A0,
                 const unsigned short* __restrict__ Bw,
                 const float* __restrict__ bias,
                 unsigned short* Out,
                 unsigned char* Hq) {
    __shared__ unsigned short As[128 * 32];
    __shared__ unsigned short Bs[128 * 32];

    const int tid = threadIdx.x;
    const int wave = tid >> 6, lane = tid & 63;
    const int wr = (wave >> 1) * 64, wc = (wave & 1) * 64;
    const int lq = lane >> 4, lm = lane & 15;
    const int rowBase = blockIdx.x * 128;

    floatx4 acc[4][4];
#pragma unroll
    for (int i = 0; i < 4; ++i)
#pragma unroll
        for (int j = 0; j < 4; ++j) {
            acc[i][j][0] = 0.f; acc[i][j][1] = 0.f;
            acc[i][j][2] = 0.f; acc[i][j][3] = 0.f;
        }

    for (int k0 = 0; k0 < 128; k0 += 32) {
#pragma unroll
        for (int q = 0; q < 2; ++q) {
            int id = wave * 128 + q * 64 + lane;
            int r = id >> 2, c = id & 3;
            int grow = rowBase + r;
            if (grow > NN - 1) grow = NN - 1;
            llds16((const char*)A0 + (size_t)grow * 256 + k0 * 2 + c * 16,
                   (char*)As + (size_t)(wave * 128 + q * 64) * 16);
            llds16((const char*)Bw + (size_t)r * 256 + k0 * 2 + c * 16,
                   (char*)Bs + (size_t)(wave * 128 + q * 64) * 16);
        }
        __syncthreads();
        short8 af[4], bf_[4];
#pragma unroll
        for (int i = 0; i < 4; ++i)
            af[i] = *(const short8*)&As[(wr + i * 16 + lm) * 32 + lq * 8];
#pragma unroll
        for (int j = 0; j < 4; ++j)
            bf_[j] = *(const short8*)&Bs[(wc + j * 16 + lm) * 32 + lq * 8];
#pragma unroll
        for (int i = 0; i < 4; ++i)
#pragma unroll
            for (int j = 0; j < 4; ++j)
                acc[i][j] = __builtin_amdgcn_mfma_f32_16x16x32_bf16(
                    af[i], bf_[j], acc[i][j], 0, 0, 0);
        __syncthreads();
    }

#pragma unroll
    for (int i = 0; i < 4; ++i) {
#pragma unroll
        for (int r = 0; r < 4; ++r) {
            int row = rowBase + wr + i * 16 + lq * 4 + r;
            if (row >= NN) continue;
            size_t rb = (size_t)row * HID;
#pragma unroll
            for (int j = 0; j < 4; ++j) {
                int col = wc + j * 16 + lm;
                float v = acc[i][j][r] + bias[col];
                float rv = fmaxf(v, 0.f);
                Out[rb + col] = f2bf(rv);
                Out[rb + col + 128] = 0;
                Hq[rb + col] = f2fp8(rv);
                Hq[rb + col + 128] = 0;
            }
        }
    }
}

// ---------------------------------------------------------------------------
// Wide MFMA GEMM for the MGU steps: 64x256 tile, 256 threads = 4 waves
// (1 row-group x 4 col-groups), each wave 64x64 = 4x4 of 16x16x32.
// LDS 40 KB -> 4 blocks/CU (VGPR<=128 keeps 16 waves/CU): phase diversity
// hides the per-iter stage drain (r10: gemm ~93 -> ~75 us each).
// BK=64 + XOR bank-swizzle (chunk ^= row&7) both sides (rule #21).
// MODE 1: gate  f = sigmoid(v+b_f) -> Ff;  HF = f * Hh
// MODE 2: cand  Out = (1-f)*h + f*tanh(v+b_h); Hq = fp8(Out)
// ---------------------------------------------------------------------------
template <int MODE>
__global__ __launch_bounds__(256, 4)
void gemm_wide(const unsigned short* __restrict__ A0,
               const unsigned short* __restrict__ A1,
               const unsigned short* __restrict__ Bw,
               const float* __restrict__ bias,
               const unsigned short* __restrict__ Hh,
               unsigned short* __restrict__ Ff,
               unsigned short* __restrict__ HF,
               unsigned short* __restrict__ Out,
               unsigned char* __restrict__ Hq) {
    __shared__ unsigned short As[64 * 64];    //  8 KB, rows 128 B, swizzled
    __shared__ unsigned short Bs[256 * 64];   // 32 KB

    const int tid = threadIdx.x;
    const int wave = tid >> 6, lane = tid & 63;
    const int wc = wave * 64;
    const int lq = lane >> 4, lm = lane & 15;
    const int rowBase = blockIdx.x * 64;

    floatx4 acc[4][4];
#pragma unroll
    for (int i = 0; i < 4; ++i)
#pragma unroll
        for (int j = 0; j < 4; ++j) {
            acc[i][j][0] = 0.f; acc[i][j][1] = 0.f;
            acc[i][j][2] = 0.f; acc[i][j][3] = 0.f;
        }

    for (int k0 = 0; k0 < 512; k0 += 64) {
        const unsigned short* Alo = (k0 >= 256) ? A1 : A0;
        const int kc = k0 & 255;
        // stage A: 8 KB = 2 passes x 256 threads x 16 B; source pre-swizzled
#pragma unroll
        for (int p = 0; p < 2; ++p) {
            int id = p * 256 + tid;
            int r = id >> 3, c = id & 7;
            int cs = c ^ (r & 7);
            int grow = rowBase + r;
            if (grow > NN - 1) grow = NN - 1;
            llds16((const char*)Alo + (size_t)grow * 512 + kc * 2 + cs * 16,
                   (char*)As + p * 4096 + wave * 1024);
        }
        // stage B: 32 KB = 8 passes x 256 threads x 16 B
#pragma unroll
        for (int p = 0; p < 8; ++p) {
            int id = p * 256 + tid;
            int r = id >> 3, c = id & 7;
            int cs = c ^ (r & 7);
            llds16((const char*)Bw + (size_t)r * 1024 + k0 * 2 + cs * 16,
                   (char*)Bs + p * 4096 + wave * 1024);
        }
        __syncthreads();
#pragma unroll
        for (int ks = 0; ks < 2; ++ks) {
            short8 af[4], bfr[4];
#pragma unroll
            for (int i = 0; i < 4; ++i) {
                int r = i * 16 + lm;
                int cc = (ks * 4 + lq) ^ (r & 7);      // inverse swizzle on read
                af[i] = *(const short8*)((const char*)As + r * 128 + cc * 16);
            }
#pragma unroll
            for (int j = 0; j < 4; ++j) {
                int r = wc + j * 16 + lm;
                int cc = (ks * 4 + lq) ^ (r & 7);
                bfr[j] = *(const short8*)((const char*)Bs + r * 128 + cc * 16);
            }
#pragma unroll
            for (int i = 0; i < 4; ++i)
#pragma unroll
                for (int j = 0; j < 4; ++j)
                    acc[i][j] = __builtin_amdgcn_mfma_f32_16x16x32_bf16(
                        af[i], bfr[j], acc[i][j], 0, 0, 0);
        }
        __syncthreads();
    }

    // epilogue
#pragma unroll
    for (int i = 0; i < 4; ++i) {
#pragma unroll
        for (int r = 0; r < 4; ++r) {
            int row = rowBase + i * 16 + lq * 4 + r;
            if (row >= NN) continue;
            size_t rb = (size_t)row * HID;
#pragma unroll
            for (int j = 0; j < 4; ++j) {
                int col = wc + j * 16 + lm;
                float v = acc[i][j][r] + bias[col];
                if (MODE == 1) {
                    float f = 1.f / (1.f + __expf(-v));
                    float hv = bf2f(Hh[rb + col]);
                    Ff[rb + col] = f2bf(f);
                    HF[rb + col] = f2bf(f * hv);
                } else {
                    float xc = fminf(fmaxf(v, -12.f), 12.f);
                    float e2 = __expf(2.f * xc);
                    float t = (e2 - 1.f) / (e2 + 1.f);
                    float f = bf2f(Ff[rb + col]);
                    float hv = bf2f(Hh[rb + col]);
                    float nh = (1.f - f) * hv + f * t;
                    Out[rb + col] = f2bf(nh);
                    Hq[rb + col] = f2fp8(nh);
                }
            }
        }
    }
}

// ---------------------------------------------------------------------------
// Readout
// ---------------------------------------------------------------------------
__global__ __launch_bounds__(256)
void colmean(const unsigned short* __restrict__ h, float* __restrict__ gsum) {
    int j = threadIdx.x;
    long long n0 = (long long)blockIdx.x * 256;
    float acc = 0.0f;
    for (int n = 0; n < 256; ++n) {
        long long node = n0 + n;
        if (node < NN) acc += bf2f(h[node * HID + j]);
    }
    atomicAdd(&gsum[j], acc);
}

__global__ __launch_bounds__(256)
void final_pred(const float* __restrict__ gsum, const float* __restrict__ Wp,
                const float* __restrict__ bp, float* __restrict__ out) {
    __shared__ float s[256];
    int j = threadIdx.x;
    s[j] = gsum[j] * (1.0f / (float)NN) * Wp[j];
    __syncthreads();
    for (int ofs = 128; ofs > 0; ofs >>= 1) {
        if (j < ofs) s[j] += s[j + ofs];
        __syncthreads();
    }
    if (j == 0) out[0] = s[0] + bp[0];
}

// ---------------------------------------------------------------------------
extern "C" void kernel_launch(void* const* d_in, const int* in_sizes, int n_in,
                              void* d_out, int out_size, void* d_ws, size_t ws_size,
                              hipStream_t stream) {
    const float* x      = (const float*)d_in[0];
    const int*   ei     = (const int*)d_in[1];
    const float* W_in   = (const float*)d_in[2];
    const float* b_in   = (const float*)d_in[3];
    const float* W_f    = (const float*)d_in[4];
    const float* U_f    = (const float*)d_in[5];
    const float* b_f    = (const float*)d_in[6];
    const float* W_h    = (const float*)d_in[7];
    const float* U_h    = (const float*)d_in[8];
    const float* b_h    = (const float*)d_in[9];
    const float* W_pred = (const float*)d_in[10];
    const float* b_pred = (const float*)d_in[11];
    float* out = (float*)d_out;

    char* p = (char*)d_ws;
    auto alloc = [&](size_t bytes) {
        char* r = p;
        p += (bytes + 511) & ~(size_t)511;
        return r;
    };
    int*            cnt    = (int*)alloc((size_t)NN * 4);
    int*            cursor = (int*)alloc((size_t)NN * 4);
    int*            off    = (int*)alloc((size_t)(NN + 1) * 4);
    int*            flag   = (int*)alloc(4);
    float*          gsum   = (float*)alloc(HID * 4);
    int*            loc    = (int*)alloc((size_t)NN * 4);
    int*            bsum   = (int*)alloc((size_t)NBLK * 4);
    int*            bpre   = (int*)alloc((size_t)(NBLK + 1) * 4);
    unsigned short* wcf    = (unsigned short*)alloc((size_t)256 * 512 * 2);
    unsigned short* wch    = (unsigned short*)alloc((size_t)256 * 512 * 2);
    unsigned short* wib    = (unsigned short*)alloc((size_t)128 * 128 * 2);
    int*            csr    = (int*)alloc((size_t)NE * 4);
    unsigned short* hbuf   = (unsigned short*)alloc((size_t)NN * HID * 2);
    unsigned short* mbuf   = (unsigned short*)alloc((size_t)NN * HID * 2);
    unsigned short* fbuf   = (unsigned short*)alloc((size_t)NN * HID * 2);
    unsigned short* hf     = (unsigned short*)alloc((size_t)NN * HID * 2);
    unsigned char*  hq     = (unsigned char*)alloc((size_t)NN * HID);
    unsigned short* xb     = hf;   // xb (25.6MB) used only before hf is live

    detect_i64<<<1, 64, 0, stream>>>(ei, flag);
    zero_setup<<<NBLK, 256, 0, stream>>>(cnt, cursor, gsum);
    conv_weights<<<512, 256, 0, stream>>>(W_f, U_f, W_h, U_h, W_in, wcf, wch, wib);
    conv_x<<<(NN * 128 / 4 + 255) / 256, 256, 0, stream>>>(x, xb);

    count_deg<<<(NE + 255) / 256, 256, 0, stream>>>(ei, flag, cnt);
    scan_k1<<<NBLK, 256, 0, stream>>>(cnt, loc, bsum);
    scan_k2<<<1, 512, 0, stream>>>(bsum, bpre);
    scan_k3<<<NBLK, 256, 0, stream>>>(loc, bpre, off);
    fill_csr<<<(NE + 255) / 256, 256, 0, stream>>>(ei, flag, off, cursor, csr);

    // input encode: h = relu(x @ W_in^T + b_in), zero-padded to 256 (+fp8 copy)
    gemm_encode<<<dim3((NN + 127) / 128), 256, 0, stream>>>(xb, wib, b_in, hbuf, hq);

    const int GBLK = (NN + 63) / 64;   // 1563
    for (int step = 0; step < 4; ++step) {
        agg8<<<dim3(NN / 4, 2), 256, 0, stream>>>(hq, off, csr, mbuf);
        gemm_wide<1><<<dim3(GBLK), 256, 0, stream>>>(
            mbuf, hbuf, wcf, b_f, hbuf, fbuf, hf, nullptr, nullptr);
        gemm_wide<2><<<dim3(GBLK), 256, 0, stream>>>(
            mbuf, hf, wch, b_h, hbuf, fbuf, nullptr, hbuf, hq);
    }

    colmean<<<NBLK, 256, 0, stream>>>(hbuf, gsum);
    final_pred<<<1, 256, 0, stream>>>(gsum, W_pred, b_pred, out);
}